// Round 4
// baseline (265.393 us; speedup 1.0000x reference)
//
#include <hip/hip_runtime.h>
#include <hip/hip_bf16.h>

#define DEVI __device__ __forceinline__

typedef float f32x4 __attribute__((ext_vector_type(4)));
typedef _Float16 f16x8 __attribute__((ext_vector_type(8)));
typedef short s16x8 __attribute__((ext_vector_type(8)));

constexpr int NB = 8;     // batch
constexpr int HW = 1024;  // i (query) dim
constexpr int KD = 128;   // QK reduction dim
constexpr int VD = 512;   // value dim
constexpr int NJ = 2048;  // j (key/col) dim

// workspace layout (bytes)
constexpr size_t WS_KT = 0;                                    // f16 KT[2][NB][NJ][KD] = 8.4MB
constexpr size_t WS_QB = WS_KT + (size_t)2*NB*NJ*KD*2;         // f16 QB[2][NB][HW][KD] = 4.2MB
constexpr size_t WS_MV = WS_QB + (size_t)2*NB*HW*KD*2;         // bf16 MV[NB][VD][NJ] = 16.8MB
constexpr size_t WS_D  = WS_MV + (size_t)NB*VD*NJ*2;           // f32 d_part[4][4][NB][NJ] = 1MB
constexpr size_t WS_P  = WS_D  + (size_t)4*4*NB*NJ*4;          // bf16 P [NB][ilen][NJ]
constexpr size_t WS_FULL = WS_P + (size_t)NB*HW*NJ*2;          // ~61 MiB
constexpr size_t WS_HALF = WS_P + (size_t)NB*(HW/2)*NJ*2;      // ~45 MiB (known available)

DEVI unsigned short f2bf(float x) {
    unsigned int u = __builtin_bit_cast(unsigned int, x);
    u += 0x7fffu + ((u >> 16) & 1u);
    return (unsigned short)(u >> 16);
}

// ---------------- k_prep: flat cvt q_key/p_q_key -> f16, m_val -> bf16 ----------------
__global__ void k_prep(const float* __restrict__ q0, const float* __restrict__ q1,
                       const float* __restrict__ mv,
                       unsigned short* __restrict__ QB, unsigned short* __restrict__ MV) {
    const int NQ4 = NB * HW * KD / 4;
    const int NV4 = NB * VD * NJ / 4;
    const int total = 2 * NQ4 + NV4;
    int idx = blockIdx.x * blockDim.x + threadIdx.x;
    for (; idx < total; idx += gridDim.x * blockDim.x) {
        if (idx < 2 * NQ4) {
            int s = (idx >= NQ4) ? 1 : 0;
            int i = idx - s * NQ4;
            float4 v = ((const float4*)(s ? q1 : q0))[i];
            ushort4 o;
            o.x = __builtin_bit_cast(unsigned short, (_Float16)v.x);
            o.y = __builtin_bit_cast(unsigned short, (_Float16)v.y);
            o.z = __builtin_bit_cast(unsigned short, (_Float16)v.z);
            o.w = __builtin_bit_cast(unsigned short, (_Float16)v.w);
            ((ushort4*)QB)[(size_t)s * NQ4 + i] = o;
        } else {
            int i = idx - 2 * NQ4;
            float4 v = ((const float4*)mv)[i];
            ushort4 o;
            o.x = f2bf(v.x); o.y = f2bf(v.y); o.z = f2bf(v.z); o.w = f2bf(v.w);
            ((ushort4*)MV)[i] = o;
        }
    }
}

// ---------------- k_prep_kt: transpose m_key/p_m_key [d][j] fp32 -> KT[j][d] f16 ------
__global__ __launch_bounds__(256) void k_prep_kt(
    const float* __restrict__ k0, const float* __restrict__ k1,
    unsigned short* __restrict__ KT) {
    __shared__ _Float16 Lt[64][136];
    int bid = blockIdx.x;
    int jt = bid & 31, b = (bid >> 5) & 7, src = bid >> 8;
    const float* K = (src ? k1 : k0) + (size_t)b * KD * NJ;
    int t = threadIdx.x;
#pragma unroll
    for (int rd = 0; rd < 8; ++rd) {
        int task = t + rd * 256;
        int d = task >> 4, j4 = (task & 15) * 4;
        float4 v = *(const float4*)&K[(size_t)d * NJ + jt * 64 + j4];
        Lt[j4 + 0][d] = (_Float16)v.x;
        Lt[j4 + 1][d] = (_Float16)v.y;
        Lt[j4 + 2][d] = (_Float16)v.z;
        Lt[j4 + 3][d] = (_Float16)v.w;
    }
    __syncthreads();
    _Float16* dst = (_Float16*)KT + ((size_t)(src * NB + b) * NJ + jt * 64) * KD;
#pragma unroll
    for (int rd = 0; rd < 4; ++rd) {
        int task = t + rd * 256;
        int j = task >> 4, ch = (task & 15) * 8;
        *(f16x8*)&dst[(size_t)j * KD + ch] = *(const f16x8*)&Lt[j][ch];
    }
}

// ---------------- k_stats: column sumexp, no LDS, no barriers ----------------
// grid 1024: b=bid&7; r=bid>>3: kc=r&1, jb=(r>>1)&15, is=r>>5 (0..3)
__global__ __launch_bounds__(256) void k_stats(
    const unsigned short* __restrict__ KTu, const unsigned short* __restrict__ QBu,
    float* __restrict__ d_part) {
    const _Float16* KT = (const _Float16*)KTu;
    const _Float16* QB = (const _Float16*)QBu;
    int bid = blockIdx.x;
    int b = bid & 7, r = bid >> 3;
    int kc = r & 1, jb = (r >> 1) & 15, is = r >> 5;
    int t = threadIdx.x, w = t >> 6, l = t & 63, lr = l & 15, lg = l >> 4;
    int j0 = jb * 128 + w * 32;
    const _Float16* Kp = KT + ((size_t)(kc * NB + b) * NJ) * KD;
    f16x8 bk[2][4];
#pragma unroll
    for (int tj = 0; tj < 2; ++tj)
#pragma unroll
        for (int kst = 0; kst < 4; ++kst)
            bk[tj][kst] = *(const f16x8*)&Kp[(size_t)(j0 + tj * 16 + lr) * KD + kst * 32 + lg * 8];

    float dacc[2][2];
    dacc[0][0] = dacc[0][1] = dacc[1][0] = dacc[1][1] = 0.f;

    for (int it = 0; it < 8; ++it) {
        int i0 = is * 256 + it * 32;
#pragma unroll
        for (int qc = 0; qc < 2; ++qc) {
            f16x8 aq[2][4];
#pragma unroll
            for (int ti = 0; ti < 2; ++ti)
#pragma unroll
                for (int kst = 0; kst < 4; ++kst)
                    aq[ti][kst] = *(const f16x8*)&QB[((size_t)(qc * NB + b) * HW + i0 + ti * 16 + lr) * KD + kst * 32 + lg * 8];
#pragma unroll
            for (int tj = 0; tj < 2; ++tj)
#pragma unroll
                for (int ti = 0; ti < 2; ++ti) {
                    f32x4 c = {0.f, 0.f, 0.f, 0.f};
#pragma unroll
                    for (int kst = 0; kst < 4; ++kst)
                        c = __builtin_amdgcn_mfma_f32_16x16x32_f16(aq[ti][kst], bk[tj][kst], c, 0, 0, 0);
#pragma unroll
                    for (int rr = 0; rr < 4; ++rr) dacc[qc][tj] += __expf(c[rr]);
                }
        }
    }
#pragma unroll
    for (int qc = 0; qc < 2; ++qc)
#pragma unroll
        for (int tj = 0; tj < 2; ++tj) {
            float v = dacc[qc][tj];
            v += __shfl_xor(v, 16, 64);
            v += __shfl_xor(v, 32, 64);
            if (lg == 0) {
                int br = qc * 2 + kc;
                d_part[(((size_t)is * 4 + br) * NB + b) * NJ + j0 + tj * 16 + lr] = v;
            }
        }
}

// ---------------- k_pmat: P = sum_br exp(S_br)/d_br -> bf16 P buffer ----------------
// grid 8b * (ilen/128) ib * 16 jb, 256 thr; per-wave private LDS tile, no loop barriers
__global__ __launch_bounds__(256) void k_pmat(
    const unsigned short* __restrict__ KTu, const unsigned short* __restrict__ QBu,
    const float* __restrict__ d_part, unsigned short* __restrict__ P,
    int ioff, int ilen) {
    const _Float16* KT = (const _Float16*)KTu;
    const _Float16* QB = (const _Float16*)QBu;
    __shared__ unsigned short Ps[4][32][136];   // 34.8 KB, per-wave private
    __shared__ float ivd[4][128];
    int bid = blockIdx.x;
    int b = bid & 7, r = bid >> 3;
    int jb = r & 15, ib = r >> 4;
    int t = threadIdx.x, w = t >> 6, l = t & 63, lr = l & 15, lg = l >> 4;

    for (int e = t; e < 512; e += 256) {
        int br = e >> 7, jj = e & 127;
        size_t o = ((size_t)br * NB + b) * NJ + jb * 128 + jj;
        const size_t S = (size_t)4 * NB * NJ;
        ivd[br][jj] = 1.0f / (d_part[o] + d_part[o + S] + d_part[o + 2 * S] + d_part[o + 3 * S]);
    }
    __syncthreads();

    int il0 = ib * 128 + w * 32;       // local i of wave strip
    int i0g = ioff + il0;              // global i

    for (int jc = 0; jc < 8; ++jc) {
        int jl = jc * 16 + lr;
        float iv[4];
#pragma unroll
        for (int br = 0; br < 4; ++br) iv[br] = ivd[br][jl];
        f32x4 pacc[2] = {{0.f,0.f,0.f,0.f},{0.f,0.f,0.f,0.f}};
#pragma unroll
        for (int qc = 0; qc < 2; ++qc) {
            f16x8 aq[2][4];
#pragma unroll
            for (int ti = 0; ti < 2; ++ti)
#pragma unroll
                for (int kst = 0; kst < 4; ++kst)
                    aq[ti][kst] = *(const f16x8*)&QB[((size_t)(qc * NB + b) * HW + i0g + ti * 16 + lr) * KD + kst * 32 + lg * 8];
#pragma unroll
            for (int kc = 0; kc < 2; ++kc) {
                f16x8 bk[4];
#pragma unroll
                for (int kst = 0; kst < 4; ++kst)
                    bk[kst] = *(const f16x8*)&KT[((size_t)(kc * NB + b) * NJ + jb * 128 + jl) * KD + kst * 32 + lg * 8];
                float ivb = iv[qc * 2 + kc];
#pragma unroll
                for (int ti = 0; ti < 2; ++ti) {
                    f32x4 c = {0.f, 0.f, 0.f, 0.f};
#pragma unroll
                    for (int kst = 0; kst < 4; ++kst)
                        c = __builtin_amdgcn_mfma_f32_16x16x32_f16(aq[ti][kst], bk[kst], c, 0, 0, 0);
#pragma unroll
                    for (int rr = 0; rr < 4; ++rr)
                        pacc[ti][rr] += __expf(c[rr]) * ivb;
                }
            }
        }
#pragma unroll
        for (int ti = 0; ti < 2; ++ti)
#pragma unroll
            for (int rr = 0; rr < 4; ++rr)
                Ps[w][ti * 16 + lg * 4 + rr][jc * 16 + lr] = f2bf(pacc[ti][rr]);
    }
    // per-wave epilogue: coalesced 16B stores (no barrier needed; Ps[w] is wave-private)
    unsigned short* Pl = P + ((size_t)b * ilen + il0) * NJ + jb * 128;
#pragma unroll
    for (int s = 0; s < 8; ++s) {
        int row = s * 4 + lg;
        *(s16x8*)&Pl[(size_t)row * NJ + lr * 8] = *(const s16x8*)&Ps[w][row][lr * 8];
    }
}

// ---------------- k_out: out = P @ MV^T, direct-global bf16 GEMM ----------------
// grid 8b * (ilen/64) ib * 4 vb, 256 thr; wave = 16i x 128v
__global__ __launch_bounds__(256) void k_out(
    const unsigned short* __restrict__ P, const unsigned short* __restrict__ MV,
    float* __restrict__ out, int ioff, int ilen) {
    int bid = blockIdx.x;
    int b = bid & 7, r = bid >> 3;
    int vb = r & 3, ib = r >> 2;
    int t = threadIdx.x, w = t >> 6, l = t & 63, lr = l & 15, lg = l >> 4;
    int i0l = ib * 64 + w * 16;
    const unsigned short* Pl = P + ((size_t)b * ilen + i0l + lr) * NJ;
    const unsigned short* Mb = MV + ((size_t)b * VD + vb * 128) * NJ;
    f32x4 acc[8];
#pragma unroll
    for (int tv = 0; tv < 8; ++tv) acc[tv] = (f32x4){0.f, 0.f, 0.f, 0.f};

#pragma unroll 2
    for (int kk = 0; kk < 64; ++kk) {
        s16x8 a = *(const s16x8*)&Pl[kk * 32 + lg * 8];
        s16x8 bv[8];
#pragma unroll
        for (int tv = 0; tv < 8; ++tv)
            bv[tv] = *(const s16x8*)&Mb[(size_t)(tv * 16 + lr) * NJ + kk * 32 + lg * 8];
#pragma unroll
        for (int tv = 0; tv < 8; ++tv)
            acc[tv] = __builtin_amdgcn_mfma_f32_16x16x32_bf16(a, bv[tv], acc[tv], 0, 0, 0);
    }
    float* ob = out + (size_t)b * 1048576;
    int i0g = ioff + i0l;
#pragma unroll
    for (int tv = 0; tv < 8; ++tv)
#pragma unroll
        for (int rr = 0; rr < 4; ++rr) {
            int i = i0g + lg * 4 + rr;
            int v = vb * 128 + tv * 16 + lr;
            ob[(size_t)i * VD + v] = acc[tv][rr];
        }
}

// ---------------- k_qval: copy q_val into second half of each batch ----------------
__global__ void k_qval(const float* __restrict__ qv, float* __restrict__ out) {
    int idx = blockIdx.x * blockDim.x + threadIdx.x;
    const int n4 = NB * VD * HW / 4;
    for (; idx < n4; idx += gridDim.x * blockDim.x) {
        int b = idx >> 17;
        int t4 = idx & 131071;
        float4 v = ((const float4*)qv)[idx];
        ((float4*)(out + (size_t)b * 1048576 + 524288))[t4] = v;
    }
}

extern "C" void kernel_launch(void* const* d_in, const int* in_sizes, int n_in,
                              void* d_out, int out_size, void* d_ws, size_t ws_size,
                              hipStream_t stream) {
    const float* m_key   = (const float*)d_in[0];
    const float* m_val   = (const float*)d_in[1];
    const float* q_key   = (const float*)d_in[2];
    const float* q_val   = (const float*)d_in[3];
    const float* p_m_key = (const float*)d_in[4];
    const float* p_q_key = (const float*)d_in[5];
    float* out = (float*)d_out;
    char* ws = (char*)d_ws;
    if (ws_size < WS_HALF) return;

    unsigned short* KT = (unsigned short*)(ws + WS_KT);
    unsigned short* QB = (unsigned short*)(ws + WS_QB);
    unsigned short* MV = (unsigned short*)(ws + WS_MV);
    float* d_part = (float*)(ws + WS_D);
    unsigned short* P = (unsigned short*)(ws + WS_P);

    k_prep<<<2048, 256, 0, stream>>>(q_key, p_q_key, m_val, QB, MV);
    k_prep_kt<<<512, 256, 0, stream>>>(m_key, p_m_key, KT);
    k_stats<<<1024, 256, 0, stream>>>(KT, QB, d_part);

    if (ws_size >= WS_FULL) {
        k_pmat<<<1024, 256, 0, stream>>>(KT, QB, d_part, P, 0, 1024);
        k_out<<<512, 256, 0, stream>>>(P, MV, out, 0, 1024);
    } else {
        k_pmat<<<512, 256, 0, stream>>>(KT, QB, d_part, P, 0, 512);
        k_out<<<256, 256, 0, stream>>>(P, MV, out, 0, 512);
        k_pmat<<<512, 256, 0, stream>>>(KT, QB, d_part, P, 512, 512);
        k_out<<<256, 256, 0, stream>>>(P, MV, out, 512, 512);
    }
    k_qval<<<1024, 256, 0, stream>>>(q_val, out);
}

// Round 5
// 125.239 us; speedup vs baseline: 2.1191x; 2.1191x over previous
//
#include <hip/hip_runtime.h>
#include <hip/hip_bf16.h>

#define DEVI __device__ __forceinline__

typedef float f32x4 __attribute__((ext_vector_type(4)));
typedef _Float16 f16x8 __attribute__((ext_vector_type(8)));
typedef short s16x8 __attribute__((ext_vector_type(8)));

constexpr int NB = 8;     // batch
constexpr int HW = 1024;  // i (query) dim
constexpr int KD = 128;   // QK reduction dim
constexpr int VD = 512;   // value dim
constexpr int NJ = 2048;  // j (key/col) dim

// Fragment-major layouts: [..tile..][..k-chunk..][lane 64][elem 8]
// QB_frag: f16  [2 src][8 b][64 it][4 kc][512]
// KT_frag: f16  [2 src][8 b][128 jt][4 kc][512]
// MV_frag: bf16 [8 b][32 vt][64 jc][512]
// P_frag : bf16 [8 b][ilen/16 it][64 jc][512]
constexpr size_t WS_KT = 0;                                    // 8.4MB
constexpr size_t WS_QB = WS_KT + (size_t)2*NB*NJ*KD*2;         // 4.2MB
constexpr size_t WS_MV = WS_QB + (size_t)2*NB*HW*KD*2;         // 16.8MB
constexpr size_t WS_D  = WS_MV + (size_t)NB*VD*NJ*2;           // 1MB
constexpr size_t WS_P  = WS_D  + (size_t)4*4*NB*NJ*4;
constexpr size_t WS_FULL = WS_P + (size_t)NB*HW*NJ*2;          // ~61 MiB
constexpr size_t WS_HALF = WS_P + (size_t)NB*(HW/2)*NJ*2;      // ~45 MiB (known ok)

DEVI unsigned short f2bf(float x) {
    unsigned int u = __builtin_bit_cast(unsigned int, x);
    u += 0x7fffu + ((u >> 16) & 1u);
    return (unsigned short)(u >> 16);
}

// ---------------- k_prep: q_key/p_q_key -> f16 frags, m_val -> bf16 frags ----------
__global__ void k_prep(const float* __restrict__ q0, const float* __restrict__ q1,
                       const float* __restrict__ mv,
                       unsigned short* __restrict__ QB, unsigned short* __restrict__ MV) {
    const int NTQ = 2 * NB * 64 * 4 * 64;        // 131072 lane-tasks (8 elem each)
    const int NTV = NB * 32 * 64 * 64;           // 1048576
    const int total = NTQ + NTV;
    for (int task = blockIdx.x * blockDim.x + threadIdx.x; task < total;
         task += gridDim.x * blockDim.x) {
        if (task < NTQ) {
            int l = task & 63, kc = (task >> 6) & 3, it = (task >> 8) & 63;
            int b = (task >> 14) & 7, src = task >> 17;
            int lr = l & 15, lg = l >> 4;
            const float* q = (src ? q1 : q0) + (size_t)b * HW * KD
                           + (size_t)(it * 16 + lr) * KD + kc * 32 + lg * 8;
            float4 x0 = *(const float4*)q, x1 = *(const float4*)(q + 4);
            f16x8 r;
            r[0]=(_Float16)x0.x; r[1]=(_Float16)x0.y; r[2]=(_Float16)x0.z; r[3]=(_Float16)x0.w;
            r[4]=(_Float16)x1.x; r[5]=(_Float16)x1.y; r[6]=(_Float16)x1.z; r[7]=(_Float16)x1.w;
            *(f16x8*)&QB[((((size_t)src * NB + b) * 64 + it) * 4 + kc) * 512 + l * 8] = r;
        } else {
            int t2 = task - NTQ;
            int l = t2 & 63, jc = (t2 >> 6) & 63, vt = (t2 >> 12) & 31, b = t2 >> 17;
            int lr = l & 15, lg = l >> 4;
            const float* p = mv + (size_t)b * VD * NJ + (size_t)(vt * 16 + lr) * NJ + jc * 32 + lg * 8;
            float4 x0 = *(const float4*)p, x1 = *(const float4*)(p + 4);
            s16x8 r;
            r[0]=(short)f2bf(x0.x); r[1]=(short)f2bf(x0.y); r[2]=(short)f2bf(x0.z); r[3]=(short)f2bf(x0.w);
            r[4]=(short)f2bf(x1.x); r[5]=(short)f2bf(x1.y); r[6]=(short)f2bf(x1.z); r[7]=(short)f2bf(x1.w);
            *(s16x8*)&MV[(((size_t)b * 32 + vt) * 64 + jc) * 512 + l * 8] = r;
        }
    }
}

// ---------------- k_prep_kt: K [d][j] fp32 -> f16 B-fragments ----------------
// grid: 2 src * 8 b * 32 jt64 = 512 blocks, 256 thr; tile [128 d][64 j]
__global__ __launch_bounds__(256) void k_prep_kt(
    const float* __restrict__ k0, const float* __restrict__ k1,
    unsigned short* __restrict__ KT) {
    __shared__ _Float16 Lt[64][136];
    int bid = blockIdx.x;
    int jt64 = bid & 31, b = (bid >> 5) & 7, src = bid >> 8;
    const float* K = (src ? k1 : k0) + (size_t)b * KD * NJ;
    int t = threadIdx.x;
#pragma unroll
    for (int rd = 0; rd < 8; ++rd) {
        int task = t + rd * 256;
        int d = task >> 4, j4 = (task & 15) * 4;
        float4 v = *(const float4*)&K[(size_t)d * NJ + jt64 * 64 + j4];
        Lt[j4 + 0][d] = (_Float16)v.x;
        Lt[j4 + 1][d] = (_Float16)v.y;
        Lt[j4 + 2][d] = (_Float16)v.z;
        Lt[j4 + 3][d] = (_Float16)v.w;
    }
    __syncthreads();
    int w = t >> 6, l = t & 63, lr = l & 15, lg = l >> 4;
    int jt = jt64 * 4 + w;
#pragma unroll
    for (int kc = 0; kc < 4; ++kc) {
        f16x8 v = *(const f16x8*)&Lt[w * 16 + lr][kc * 32 + lg * 8];
        *(f16x8*)&KT[((((size_t)src * NB + b) * 128 + jt) * 4 + kc) * 512 + l * 8] = v;
    }
}

// ---------------- k_stats: column sumexp, all-frag loads, no LDS ----------------
// grid 1024: b=bid&7; r=bid>>3: kc=r&1, jb=(r>>1)&15, is=r>>5 (0..3)
__global__ __launch_bounds__(256) void k_stats(
    const unsigned short* __restrict__ KTu, const unsigned short* __restrict__ QBu,
    float* __restrict__ d_part) {
    int bid = blockIdx.x;
    int b = bid & 7, r = bid >> 3;
    int kc_s = r & 1, jb = (r >> 1) & 15, is = r >> 5;
    int t = threadIdx.x, w = t >> 6, l = t & 63, lr = l & 15, lg = l >> 4;
    f16x8 bk[2][4];
#pragma unroll
    for (int tj = 0; tj < 2; ++tj) {
        int jt = jb * 8 + w * 2 + tj;
#pragma unroll
        for (int kst = 0; kst < 4; ++kst)
            bk[tj][kst] = *(const f16x8*)&KTu[((((size_t)kc_s * NB + b) * 128 + jt) * 4 + kst) * 512 + l * 8];
    }
    float dacc[2][2];
    dacc[0][0] = dacc[0][1] = dacc[1][0] = dacc[1][1] = 0.f;

    for (int it = 0; it < 8; ++it) {
#pragma unroll
        for (int qc = 0; qc < 2; ++qc) {
            f16x8 aq[2][4];
#pragma unroll
            for (int ti = 0; ti < 2; ++ti) {
                int itile = is * 16 + it * 2 + ti;
#pragma unroll
                for (int kst = 0; kst < 4; ++kst)
                    aq[ti][kst] = *(const f16x8*)&QBu[((((size_t)qc * NB + b) * 64 + itile) * 4 + kst) * 512 + l * 8];
            }
#pragma unroll
            for (int tj = 0; tj < 2; ++tj)
#pragma unroll
                for (int ti = 0; ti < 2; ++ti) {
                    f32x4 c = {0.f, 0.f, 0.f, 0.f};
#pragma unroll
                    for (int kst = 0; kst < 4; ++kst)
                        c = __builtin_amdgcn_mfma_f32_16x16x32_f16(aq[ti][kst], bk[tj][kst], c, 0, 0, 0);
#pragma unroll
                    for (int rr = 0; rr < 4; ++rr) dacc[qc][tj] += __expf(c[rr]);
                }
        }
    }
#pragma unroll
    for (int qc = 0; qc < 2; ++qc)
#pragma unroll
        for (int tj = 0; tj < 2; ++tj) {
            float v = dacc[qc][tj];
            v += __shfl_xor(v, 16, 64);
            v += __shfl_xor(v, 32, 64);
            if (lg == 0) {
                int br = qc * 2 + kc_s;
                int j = jb * 128 + w * 32 + tj * 16 + lr;
                d_part[(((size_t)is * 4 + br) * NB + b) * NJ + j] = v;
            }
        }
}

// ---------------- k_pmat: P = sum_br exp(S_br)/d_br -> bf16 P fragments ----------
// grid 8b * 16jb * (ilen/128) ib, 256 thr; per-wave private LDS transpose
__global__ __launch_bounds__(256) void k_pmat(
    const unsigned short* __restrict__ KTu, const unsigned short* __restrict__ QBu,
    const float* __restrict__ d_part, unsigned short* __restrict__ P,
    int ioff, int ilen) {
    __shared__ unsigned short Ps[4][32][144];   // 36 KB, wave-private strips
    __shared__ float ivd[4][128];
    int bid = blockIdx.x;
    int b = bid & 7, r = bid >> 3;
    int jb = r & 15, ib = r >> 4;
    int t = threadIdx.x, w = t >> 6, l = t & 63, lr = l & 15, lg = l >> 4;

    for (int e = t; e < 512; e += 256) {
        int br = e >> 7, jj = e & 127;
        size_t o = ((size_t)br * NB + b) * NJ + jb * 128 + jj;
        const size_t S = (size_t)4 * NB * NJ;
        ivd[br][jj] = 1.0f / (d_part[o] + d_part[o + S] + d_part[o + 2 * S] + d_part[o + 3 * S]);
    }
    __syncthreads();

    int it_g0 = (ioff >> 4) + ib * 8 + w * 2;    // global i-tile base of wave strip
    int nit = ilen >> 4;
    int it_l0 = ib * 8 + w * 2;                  // local i-tile base

    for (int jc = 0; jc < 8; ++jc) {
        int jt = jb * 8 + jc;
        float iv[4];
#pragma unroll
        for (int br = 0; br < 4; ++br) iv[br] = ivd[br][jc * 16 + lr];
        f32x4 pacc[2] = {{0.f,0.f,0.f,0.f},{0.f,0.f,0.f,0.f}};
#pragma unroll
        for (int qc = 0; qc < 2; ++qc) {
            f16x8 aq[2][4];
#pragma unroll
            for (int ti = 0; ti < 2; ++ti)
#pragma unroll
                for (int kst = 0; kst < 4; ++kst)
                    aq[ti][kst] = *(const f16x8*)&QBu[((((size_t)qc * NB + b) * 64 + it_g0 + ti) * 4 + kst) * 512 + l * 8];
#pragma unroll
            for (int kc = 0; kc < 2; ++kc) {
                f16x8 bk[4];
#pragma unroll
                for (int kst = 0; kst < 4; ++kst)
                    bk[kst] = *(const f16x8*)&KTu[((((size_t)kc * NB + b) * 128 + jt) * 4 + kst) * 512 + l * 8];
                float ivb = iv[qc * 2 + kc];
#pragma unroll
                for (int ti = 0; ti < 2; ++ti) {
                    f32x4 c = {0.f, 0.f, 0.f, 0.f};
#pragma unroll
                    for (int kst = 0; kst < 4; ++kst)
                        c = __builtin_amdgcn_mfma_f32_16x16x32_f16(aq[ti][kst], bk[kst], c, 0, 0, 0);
#pragma unroll
                    for (int rr = 0; rr < 4; ++rr)
                        pacc[ti][rr] += __expf(c[rr]) * ivb;
                }
            }
        }
#pragma unroll
        for (int ti = 0; ti < 2; ++ti)
#pragma unroll
            for (int rr = 0; rr < 4; ++rr)
                Ps[w][ti * 16 + lg * 4 + rr][jc * 16 + lr] = f2bf(pacc[ti][rr]);
    }
    // wave-private epilogue: read back as A-fragments, store contiguous
#pragma unroll
    for (int it2 = 0; it2 < 2; ++it2)
#pragma unroll
        for (int jc32 = 0; jc32 < 4; ++jc32) {
            s16x8 v = *(const s16x8*)&Ps[w][it2 * 16 + lr][jc32 * 32 + lg * 8];
            size_t o = (((size_t)b * nit + it_l0 + it2) * 64 + jb * 4 + jc32) * 512 + l * 8;
            *(s16x8*)&P[o] = v;
        }
}

// ---------------- k_out: out = P @ MV^T; frag loads + dbuf LDS B-sharing ---------
// grid 8b * (ilen/64) ib * 4 vb, 256 thr; wave = 16i x 128v
__global__ __launch_bounds__(256) void k_out(
    const unsigned short* __restrict__ Pf, const unsigned short* __restrict__ MVf,
    float* __restrict__ out, int ioff, int ilen) {
    __shared__ unsigned short Bs[2][8][512];    // 16 KB double-buffered B frags
    int bid = blockIdx.x;
    int b = bid & 7, r = bid >> 3;
    int vb = r & 3, ib = r >> 2;
    int t = threadIdx.x, w = t >> 6, l = t & 63, lr = l & 15, lg = l >> 4;
    int nit = ilen >> 4;
    const unsigned short* Pw = Pf + (((size_t)b * nit + ib * 4 + w) * 64) * 512 + l * 8;
    int svt = t >> 5, soff = (t & 31) * 16;
    const unsigned short* Ms = MVf + (((size_t)b * 32 + vb * 8 + svt) * 64) * 512 + soff;

    {   s16x8 v0 = *(const s16x8*)&Ms[0];
        s16x8 v1 = *(const s16x8*)&Ms[8];
        *(s16x8*)&Bs[0][svt][soff] = v0;
        *(s16x8*)&Bs[0][svt][soff + 8] = v1; }
    __syncthreads();

    f32x4 acc[8];
#pragma unroll
    for (int tv = 0; tv < 8; ++tv) acc[tv] = (f32x4){0.f, 0.f, 0.f, 0.f};

    for (int kk = 0; kk < 64; ++kk) {
        int cur = kk & 1;
        if (kk < 63) {
            const unsigned short* Mn = Ms + (size_t)(kk + 1) * 512;
            s16x8 v0 = *(const s16x8*)&Mn[0];
            s16x8 v1 = *(const s16x8*)&Mn[8];
            *(s16x8*)&Bs[cur ^ 1][svt][soff] = v0;
            *(s16x8*)&Bs[cur ^ 1][svt][soff + 8] = v1;
        }
        s16x8 pa = *(const s16x8*)&Pw[(size_t)kk * 512];
        s16x8 bv[8];
#pragma unroll
        for (int tv = 0; tv < 8; ++tv) bv[tv] = *(const s16x8*)&Bs[cur][tv][l * 8];
#pragma unroll
        for (int tv = 0; tv < 8; ++tv)
            acc[tv] = __builtin_amdgcn_mfma_f32_16x16x32_bf16(pa, bv[tv], acc[tv], 0, 0, 0);
        __syncthreads();
    }
    float* ob = out + (size_t)b * 1048576;
    int i0 = ioff + (ib * 4 + w) * 16;
#pragma unroll
    for (int tv = 0; tv < 8; ++tv)
#pragma unroll
        for (int rr = 0; rr < 4; ++rr) {
            int i = i0 + lg * 4 + rr;
            int v = vb * 128 + tv * 16 + lr;
            ob[(size_t)i * VD + v] = acc[tv][rr];
        }
}

// ---------------- k_qval: copy q_val into second half of each batch ----------------
__global__ void k_qval(const float* __restrict__ qv, float* __restrict__ out) {
    int idx = blockIdx.x * blockDim.x + threadIdx.x;
    const int n4 = NB * VD * HW / 4;
    for (; idx < n4; idx += gridDim.x * blockDim.x) {
        int b = idx >> 17;
        int t4 = idx & 131071;
        float4 v = ((const float4*)qv)[idx];
        ((float4*)(out + (size_t)b * 1048576 + 524288))[t4] = v;
    }
}

extern "C" void kernel_launch(void* const* d_in, const int* in_sizes, int n_in,
                              void* d_out, int out_size, void* d_ws, size_t ws_size,
                              hipStream_t stream) {
    const float* m_key   = (const float*)d_in[0];
    const float* m_val   = (const float*)d_in[1];
    const float* q_key   = (const float*)d_in[2];
    const float* q_val   = (const float*)d_in[3];
    const float* p_m_key = (const float*)d_in[4];
    const float* p_q_key = (const float*)d_in[5];
    float* out = (float*)d_out;
    char* ws = (char*)d_ws;
    if (ws_size < WS_HALF) return;

    unsigned short* KT = (unsigned short*)(ws + WS_KT);
    unsigned short* QB = (unsigned short*)(ws + WS_QB);
    unsigned short* MV = (unsigned short*)(ws + WS_MV);
    float* d_part = (float*)(ws + WS_D);
    unsigned short* P = (unsigned short*)(ws + WS_P);

    k_prep<<<2048, 256, 0, stream>>>(q_key, p_q_key, m_val, QB, MV);
    k_prep_kt<<<512, 256, 0, stream>>>(m_key, p_m_key, KT);
    k_stats<<<1024, 256, 0, stream>>>(KT, QB, d_part);

    if (ws_size >= WS_FULL) {
        k_pmat<<<1024, 256, 0, stream>>>(KT, QB, d_part, P, 0, 1024);
        k_out<<<512, 256, 0, stream>>>(P, MV, out, 0, 1024);
    } else {
        k_pmat<<<512, 256, 0, stream>>>(KT, QB, d_part, P, 0, 512);
        k_out<<<256, 256, 0, stream>>>(P, MV, out, 0, 512);
        k_pmat<<<512, 256, 0, stream>>>(KT, QB, d_part, P, 512, 512);
        k_out<<<256, 256, 0, stream>>>(P, MV, out, 512, 512);
    }
    k_qval<<<1024, 256, 0, stream>>>(q_val, out);
}

// Round 7
// 105.947 us; speedup vs baseline: 2.5050x; 1.1821x over previous
//
#include <hip/hip_runtime.h>
#include <hip/hip_bf16.h>

#define DEVI __device__ __forceinline__

typedef float f32x4 __attribute__((ext_vector_type(4)));
typedef _Float16 f16x8 __attribute__((ext_vector_type(8)));
typedef short s16x8 __attribute__((ext_vector_type(8)));

constexpr int NB = 8;     // batch
constexpr int HW = 1024;  // i (query) dim
constexpr int KD = 128;   // QK reduction dim
constexpr int VD = 512;   // value dim
constexpr int NJ = 2048;  // j (key/col) dim

// Fragment-major layouts: [..tile..][..k-chunk..][lane 64][elem 8]
// QB f16  [2 src][8 b][64 it][4 kc][512]
// KT f16  [2 src][8 b][128 jt][4 kc][512]
// MV bf16 [8 b][32 vt][64 jc][512]
// P  bf16 [8 b][32 itl][64 jc][512]  x2 halves: i<512 -> ws, i>=512 -> d_out q_val half
constexpr size_t WS_KT = 0;                                    // 8.39 MB
constexpr size_t WS_QB = WS_KT + (size_t)2*NB*NJ*KD*2;         // 4.19 MB
constexpr size_t WS_MV = WS_QB + (size_t)2*NB*HW*KD*2;         // 16.78 MB
constexpr size_t WS_D  = WS_MV + (size_t)NB*VD*NJ*2;           // 2.10 MB
constexpr size_t WS_P0 = WS_D  + (size_t)4*4*NB*NJ*4;          // 16.78 MB
constexpr size_t WS_NEED = WS_P0 + (size_t)NB*(HW/2)*NJ*2;     // 48.2 MB = 46.0 MiB (proven ok)
constexpr size_t PB_STRIDE = (size_t)32*64*512;                // shorts per batch per P half

DEVI unsigned short f2bf(float x) {
    unsigned int u = __builtin_bit_cast(unsigned int, x);
    u += 0x7fffu + ((u >> 16) & 1u);
    return (unsigned short)(u >> 16);
}

// ---------------- k_prep: q_key/p_q_key -> f16 frags, m_val -> bf16 frags ----------
__global__ void k_prep(const float* __restrict__ q0, const float* __restrict__ q1,
                       const float* __restrict__ mv,
                       unsigned short* __restrict__ QB, unsigned short* __restrict__ MV) {
    const int NTQ = 2 * NB * 64 * 4 * 64;        // 262144 lane-tasks (8 elem each)
    const int NTV = NB * 32 * 64 * 64;           // 1048576
    const int total = NTQ + NTV;
    for (int task = blockIdx.x * blockDim.x + threadIdx.x; task < total;
         task += gridDim.x * blockDim.x) {
        if (task < NTQ) {
            int l = task & 63, kc = (task >> 6) & 3, it = (task >> 8) & 63;
            int b = (task >> 14) & 7, src = task >> 17;
            int lr = l & 15, lg = l >> 4;
            const float* q = (src ? q1 : q0) + (size_t)b * HW * KD
                           + (size_t)(it * 16 + lr) * KD + kc * 32 + lg * 8;
            float4 x0 = *(const float4*)q, x1 = *(const float4*)(q + 4);
            f16x8 r;
            r[0]=(_Float16)x0.x; r[1]=(_Float16)x0.y; r[2]=(_Float16)x0.z; r[3]=(_Float16)x0.w;
            r[4]=(_Float16)x1.x; r[5]=(_Float16)x1.y; r[6]=(_Float16)x1.z; r[7]=(_Float16)x1.w;
            *(f16x8*)&QB[((((size_t)src * NB + b) * 64 + it) * 4 + kc) * 512 + l * 8] = r;
        } else {
            int t2 = task - NTQ;
            int l = t2 & 63, jc = (t2 >> 6) & 63, vt = (t2 >> 12) & 31, b = t2 >> 17;
            int lr = l & 15, lg = l >> 4;
            const float* p = mv + (size_t)b * VD * NJ + (size_t)(vt * 16 + lr) * NJ + jc * 32 + lg * 8;
            float4 x0 = *(const float4*)p, x1 = *(const float4*)(p + 4);
            s16x8 r;
            r[0]=(short)f2bf(x0.x); r[1]=(short)f2bf(x0.y); r[2]=(short)f2bf(x0.z); r[3]=(short)f2bf(x0.w);
            r[4]=(short)f2bf(x1.x); r[5]=(short)f2bf(x1.y); r[6]=(short)f2bf(x1.z); r[7]=(short)f2bf(x1.w);
            *(s16x8*)&MV[(((size_t)b * 32 + vt) * 64 + jc) * 512 + l * 8] = r;
        }
    }
}

// ---------------- k_prep_kt: K [d][j] fp32 -> f16 B-fragments ----------------
__global__ __launch_bounds__(256) void k_prep_kt(
    const float* __restrict__ k0, const float* __restrict__ k1,
    unsigned short* __restrict__ KT) {
    __shared__ _Float16 Lt[64][136];
    int bid = blockIdx.x;
    int jt64 = bid & 31, b = (bid >> 5) & 7, src = bid >> 8;
    const float* K = (src ? k1 : k0) + (size_t)b * KD * NJ;
    int t = threadIdx.x;
#pragma unroll
    for (int rd = 0; rd < 8; ++rd) {
        int task = t + rd * 256;
        int d = task >> 4, j4 = (task & 15) * 4;
        float4 v = *(const float4*)&K[(size_t)d * NJ + jt64 * 64 + j4];
        Lt[j4 + 0][d] = (_Float16)v.x;
        Lt[j4 + 1][d] = (_Float16)v.y;
        Lt[j4 + 2][d] = (_Float16)v.z;
        Lt[j4 + 3][d] = (_Float16)v.w;
    }
    __syncthreads();
    int w = t >> 6, l = t & 63, lr = l & 15, lg = l >> 4;
    int jt = jt64 * 4 + w;
#pragma unroll
    for (int kc = 0; kc < 4; ++kc) {
        f16x8 v = *(const f16x8*)&Lt[w * 16 + lr][kc * 32 + lg * 8];
        *(f16x8*)&KT[((((size_t)src * NB + b) * 128 + jt) * 4 + kc) * 512 + l * 8] = v;
    }
}

// ---------------- k_stats: column sumexp; <=128 VGPR, 4 blocks/CU ----------------
// grid 1024: b=bid&7; r=bid>>3: jb=r&15, is=(r>>4)&3, kc=r>>6
__global__ __launch_bounds__(256, 4) void k_stats(
    const unsigned short* __restrict__ KTu, const unsigned short* __restrict__ QBu,
    float* __restrict__ d_part) {
    int bid = blockIdx.x;
    int b = bid & 7, r = bid >> 3;
    int jb = r & 15, is = (r >> 4) & 3, kc_s = r >> 6;
    int t = threadIdx.x, w = t >> 6, l = t & 63, lr = l & 15, lg = l >> 4;
    f16x8 bk[2][4];
#pragma unroll
    for (int tj = 0; tj < 2; ++tj) {
        int jt = jb * 8 + w * 2 + tj;
#pragma unroll
        for (int kst = 0; kst < 4; ++kst)
            bk[tj][kst] = *(const f16x8*)&KTu[((((size_t)kc_s * NB + b) * 128 + jt) * 4 + kst) * 512 + l * 8];
    }
    float dacc[2][2];
    dacc[0][0] = dacc[0][1] = dacc[1][0] = dacc[1][1] = 0.f;

#pragma unroll 2
    for (int it = 0; it < 16; ++it) {
        int itile = is * 16 + it;
#pragma unroll
        for (int qc = 0; qc < 2; ++qc) {
            f16x8 aq[4];
#pragma unroll
            for (int kst = 0; kst < 4; ++kst)
                aq[kst] = *(const f16x8*)&QBu[((((size_t)qc * NB + b) * 64 + itile) * 4 + kst) * 512 + l * 8];
#pragma unroll
            for (int tj = 0; tj < 2; ++tj) {
                f32x4 c = {0.f, 0.f, 0.f, 0.f};
#pragma unroll
                for (int kst = 0; kst < 4; ++kst)
                    c = __builtin_amdgcn_mfma_f32_16x16x32_f16(aq[kst], bk[tj][kst], c, 0, 0, 0);
#pragma unroll
                for (int rr = 0; rr < 4; ++rr) dacc[qc][tj] += __expf(c[rr]);
            }
        }
    }
#pragma unroll
    for (int qc = 0; qc < 2; ++qc)
#pragma unroll
        for (int tj = 0; tj < 2; ++tj) {
            float v = dacc[qc][tj];
            v += __shfl_xor(v, 16, 64);
            v += __shfl_xor(v, 32, 64);
            if (lg == 0) {
                int br = qc * 2 + kc_s;
                int j = (jb * 8 + w * 2 + tj) * 16 + lr;
                d_part[(((size_t)is * 4 + br) * NB + b) * NJ + j] = v;
            }
        }
}

// ---------------- k_pmat: P = sum_br exp(S_br)/d_br -> bf16 frags (split halves) ----
// grid 1024: b=bid&7; r=bid>>3: jb=r&15, ib=r>>4 (128 i per block)
__global__ __launch_bounds__(256, 4) void k_pmat(
    const unsigned short* __restrict__ KTu, const unsigned short* __restrict__ QBu,
    const float* __restrict__ d_part, unsigned short* __restrict__ P0,
    float* out) {
    __shared__ unsigned short Ps[4][32][136];   // 34.8 KB wave-private strips
    __shared__ float ivd[4][128];
    int bid = blockIdx.x;
    int b = bid & 7, r = bid >> 3;
    int jb = r & 15, ib = r >> 4;
    int t = threadIdx.x, w = t >> 6, l = t & 63, lr = l & 15, lg = l >> 4;

    for (int e = t; e < 512; e += 256) {
        int br = e >> 7, jj = e & 127;
        size_t o = ((size_t)br * NB + b) * NJ + jb * 128 + jj;
        const size_t S = (size_t)4 * NB * NJ;
        ivd[br][jj] = 1.0f / (d_part[o] + d_part[o + S] + d_part[o + 2 * S] + d_part[o + 3 * S]);
    }
    __syncthreads();

    // hoisted A fragments: 16 frags = 64 VGPR, loaded once
    f16x8 aq[2][2][4];
#pragma unroll
    for (int qc = 0; qc < 2; ++qc)
#pragma unroll
        for (int ti = 0; ti < 2; ++ti)
#pragma unroll
            for (int kst = 0; kst < 4; ++kst)
                aq[qc][ti][kst] = *(const f16x8*)&QBu[((((size_t)qc * NB + b) * 64 + ib * 8 + w * 2 + ti) * 4 + kst) * 512 + l * 8];

#pragma unroll 1
    for (int jc = 0; jc < 8; ++jc) {
        int jt = jb * 8 + jc;
        float iv[4];
#pragma unroll
        for (int br = 0; br < 4; ++br) iv[br] = ivd[br][jc * 16 + lr];
        f32x4 pacc[2] = {{0.f,0.f,0.f,0.f},{0.f,0.f,0.f,0.f}};
#pragma unroll
        for (int kc = 0; kc < 2; ++kc) {
            f16x8 bk[4];
#pragma unroll
            for (int kst = 0; kst < 4; ++kst)
                bk[kst] = *(const f16x8*)&KTu[((((size_t)kc * NB + b) * 128 + jt) * 4 + kst) * 512 + l * 8];
#pragma unroll
            for (int qc = 0; qc < 2; ++qc) {
                float ivb = iv[qc * 2 + kc];
#pragma unroll
                for (int ti = 0; ti < 2; ++ti) {
                    f32x4 c = {0.f, 0.f, 0.f, 0.f};
#pragma unroll
                    for (int kst = 0; kst < 4; ++kst)
                        c = __builtin_amdgcn_mfma_f32_16x16x32_f16(aq[qc][ti][kst], bk[kst], c, 0, 0, 0);
#pragma unroll
                    for (int rr = 0; rr < 4; ++rr)
                        pacc[ti][rr] += __expf(c[rr]) * ivb;
                }
            }
        }
#pragma unroll
        for (int ti = 0; ti < 2; ++ti)
#pragma unroll
            for (int rr = 0; rr < 4; ++rr)
                Ps[w][ti * 16 + lg * 4 + rr][jc * 16 + lr] = f2bf(pacc[ti][rr]);
    }
    // wave-private epilogue: read back as A-fragments, store to the right P half
    unsigned short* Pg;
    int itl_base;
    if (ib < 4) { Pg = P0 + (size_t)b * PB_STRIDE; itl_base = ib * 8 + w * 2; }
    else { Pg = (unsigned short*)(out + (size_t)b * 1048576 + 524288); itl_base = (ib - 4) * 8 + w * 2; }
#pragma unroll
    for (int it2 = 0; it2 < 2; ++it2)
#pragma unroll
        for (int jcq = 0; jcq < 4; ++jcq) {
            s16x8 v = *(const s16x8*)&Ps[w][it2 * 16 + lr][jcq * 32 + lg * 8];
            size_t o = (((size_t)(itl_base + it2)) * 64 + jb * 4 + jcq) * 512 + l * 8;
            *(s16x8*)&Pg[o] = v;
        }
}

// ---------------- k_out: out = P @ MV^T; all direct-global frag loads, no LDS ------
// grid 512: b=bid&7; r=bid>>3: vb=r&3, ibb=r>>2 (in [0,16), 64 i rows each)
// 4 waves as 2(i) x 2(v); wave = 2 it-tiles x 4 vt-tiles (32 i x 64 v)
__global__ __launch_bounds__(256) void k_out(
    const unsigned short* __restrict__ P0, const unsigned short* __restrict__ MVf,
    float* out) {
    int bid = blockIdx.x;
    int b = bid & 7, r = bid >> 3;
    int vb = r & 3, ibb = r >> 2;
    int t = threadIdx.x, w = t >> 6, l = t & 63, lr = l & 15, lg = l >> 4;
    int wi = w >> 1, wv = w & 1;
    int it0 = ibb * 4 + wi * 2;            // wave's first global it-tile
    const unsigned short* Pb;
    int itl0;
    if (ibb < 8) { Pb = P0 + (size_t)b * PB_STRIDE; itl0 = it0; }
    else { Pb = (const unsigned short*)(out + (size_t)b * 1048576 + 524288); itl0 = it0 - 32; }
    const unsigned short* pA0 = Pb + ((size_t)itl0 * 64) * 512 + l * 8;
    const unsigned short* pA1 = Pb + ((size_t)(itl0 + 1) * 64) * 512 + l * 8;
    int vt0 = vb * 8 + wv * 4;
    const unsigned short* pB = MVf + (((size_t)b * 32 + vt0) * 64) * 512 + l * 8;

    f32x4 acc[2][4];
#pragma unroll
    for (int ii = 0; ii < 2; ++ii)
#pragma unroll
        for (int tv = 0; tv < 4; ++tv) acc[ii][tv] = (f32x4){0.f, 0.f, 0.f, 0.f};

    s16x8 a0 = *(const s16x8*)&pA0[0];
    s16x8 a1 = *(const s16x8*)&pA1[0];
    s16x8 bv[4];
#pragma unroll
    for (int tv = 0; tv < 4; ++tv) bv[tv] = *(const s16x8*)&pB[(size_t)tv * 64 * 512];

    for (int jc = 0; jc < 64; ++jc) {
        s16x8 a0n = a0, a1n = a1, bn[4];
#pragma unroll
        for (int tv = 0; tv < 4; ++tv) bn[tv] = bv[tv];
        if (jc < 63) {
            a0n = *(const s16x8*)&pA0[(size_t)(jc + 1) * 512];
            a1n = *(const s16x8*)&pA1[(size_t)(jc + 1) * 512];
#pragma unroll
            for (int tv = 0; tv < 4; ++tv)
                bn[tv] = *(const s16x8*)&pB[(size_t)tv * 64 * 512 + (size_t)(jc + 1) * 512];
        }
#pragma unroll
        for (int tv = 0; tv < 4; ++tv) {
            acc[0][tv] = __builtin_amdgcn_mfma_f32_16x16x32_bf16(a0, bv[tv], acc[0][tv], 0, 0, 0);
            acc[1][tv] = __builtin_amdgcn_mfma_f32_16x16x32_bf16(a1, bv[tv], acc[1][tv], 0, 0, 0);
        }
        a0 = a0n; a1 = a1n;
#pragma unroll
        for (int tv = 0; tv < 4; ++tv) bv[tv] = bn[tv];
    }
    float* ob = out + (size_t)b * 1048576;
#pragma unroll
    for (int ii = 0; ii < 2; ++ii)
#pragma unroll
        for (int tv = 0; tv < 4; ++tv)
#pragma unroll
            for (int rr = 0; rr < 4; ++rr) {
                int i = (it0 + ii) * 16 + lg * 4 + rr;
                int v = (vt0 + tv) * 16 + lr;
                ob[(size_t)i * VD + v] = acc[ii][tv][rr];
            }
}

// ---------------- k_qval: copy q_val into second half (LAST — overwrites P1) -------
__global__ void k_qval(const float* __restrict__ qv, float* __restrict__ out) {
    int idx = blockIdx.x * blockDim.x + threadIdx.x;
    const int n4 = NB * VD * HW / 4;
    for (; idx < n4; idx += gridDim.x * blockDim.x) {
        int b = idx >> 17;
        int t4 = idx & 131071;
        float4 v = ((const float4*)qv)[idx];
        ((float4*)(out + (size_t)b * 1048576 + 524288))[t4] = v;
    }
}

extern "C" void kernel_launch(void* const* d_in, const int* in_sizes, int n_in,
                              void* d_out, int out_size, void* d_ws, size_t ws_size,
                              hipStream_t stream) {
    const float* m_key   = (const float*)d_in[0];
    const float* m_val   = (const float*)d_in[1];
    const float* q_key   = (const float*)d_in[2];
    const float* q_val   = (const float*)d_in[3];
    const float* p_m_key = (const float*)d_in[4];
    const float* p_q_key = (const float*)d_in[5];
    float* out = (float*)d_out;
    char* ws = (char*)d_ws;
    if (ws_size < WS_NEED) return;

    unsigned short* KT = (unsigned short*)(ws + WS_KT);
    unsigned short* QB = (unsigned short*)(ws + WS_QB);
    unsigned short* MV = (unsigned short*)(ws + WS_MV);
    float* d_part = (float*)(ws + WS_D);
    unsigned short* P0 = (unsigned short*)(ws + WS_P0);

    k_prep<<<2048, 256, 0, stream>>>(q_key, p_q_key, m_val, QB, MV);
    k_prep_kt<<<512, 256, 0, stream>>>(m_key, p_m_key, KT);
    k_stats<<<1024, 256, 0, stream>>>(KT, QB, d_part);
    k_pmat<<<1024, 256, 0, stream>>>(KT, QB, d_part, P0, out);  // P -> ws half + d_out half
    k_out<<<512, 256, 0, stream>>>(P0, MV, out);                // reads P, writes branch half
    k_qval<<<1024, 256, 0, stream>>>(q_val, out);               // overwrites P1 with q_val
}